// Round 20
// baseline (240.868 us; speedup 1.0000x reference)
//
#include <hip/hip_runtime.h>
#include <hip/hip_bf16.h>

typedef __bf16 bf16_t;
typedef __bf16 bf16x8 __attribute__((ext_vector_type(8)));
typedef float f32x4 __attribute__((ext_vector_type(4)));

__device__ __forceinline__ unsigned short f32_to_bf16_rn(float f) {
  unsigned u = __float_as_uint(f);
  u += 0x7fffu + ((u >> 16) & 1u);
  return (unsigned short)(u >> 16);
}

__device__ __forceinline__ ushort4 cvt4(float4 v) {
  ushort4 o;
  o.x = f32_to_bf16_rn(v.x);
  o.y = f32_to_bf16_rn(v.y);
  o.z = f32_to_bf16_rn(v.z);
  o.w = f32_to_bf16_rn(v.w);
  return o;
}

__device__ __forceinline__ float gelu_exact(float x) {
  return 0.5f * x * (1.0f + erff(x * 0.7071067811865475f));
}

#define GLDS16(g, l)                                                          \
  __builtin_amdgcn_global_load_lds(                                           \
      (const __attribute__((address_space(1))) void*)(g),                     \
      (__attribute__((address_space(3))) void*)(l), 16, 0, 0)

// ---------------- build compacted index list (deterministic scan) ----------
__global__ void build_idx_kernel(const float* __restrict__ mask1,
                                 const float* __restrict__ mask2,
                                 int* __restrict__ idx, int* __restrict__ meta,
                                 int H, int D) {
  __shared__ int sums[1024];
  const int t = threadIdx.x;
  int flags[8];
  int tot = 0;
#pragma unroll
  for (int u = 0; u < 8; ++u) {
    int j = t * 8 + u;
    int f = (mask1[(long long)j * D] != 0.0f) && (mask2[j] != 0.0f);
    flags[u] = f;
    tot += f;
  }
  sums[t] = tot;
  __syncthreads();
  for (int off = 1; off < 1024; off <<= 1) {
    int v = (t >= off) ? sums[t - off] : 0;
    __syncthreads();
    sums[t] += v;
    __syncthreads();
  }
  int pos = sums[t] - tot;
#pragma unroll
  for (int u = 0; u < 8; ++u) {
    if (flags[u]) idx[pos++] = t * 8 + u;
  }
  if (t == 1023) {
    int count = sums[1023];
    meta[0] = count;
    meta[1] = (count + 127) & ~127;  // kpad: multiple of 128
  }
}

// -- fused prep: cast x -> bf16, compact+cast w1 rows, compact+cast w2 cols --
// All memory-bound (~276MB traffic ≈ 44us); keeping the w2 gather HERE (not
// inside GEMM1's launch) keeps GEMM1 clean — R15/R19 showed the piggyback
// costs GEMM1 ~60us of interference while saving only ~11us of prep.
__global__ void prep_kernel(const float* __restrict__ x,
                            const float* __restrict__ w1,
                            const float* __restrict__ w2,
                            const int* __restrict__ idx,
                            const int* __restrict__ meta,
                            unsigned short* __restrict__ xb,
                            unsigned short* __restrict__ w1c,
                            unsigned short* __restrict__ w2c, int D, int H) {
  const int nx = 4194304;  // M*D/4 quads
  const int count = meta[0];
  const int kpad = meta[1];
  const int nw1 = kpad << 9;  // kpad * D/4 quads
  const int nw2 = 2097152;    // D * KP/4 quads (ld 4096)
  const int total = nx + nw1 + nw2;
  for (int i = blockIdx.x * 256 + threadIdx.x; i < total; i += 2048 * 256) {
    if (i < nx) {
      ((ushort4*)xb)[i] = cvt4(((const float4*)x)[i]);
    } else if (i < nx + nw1) {
      int q = i - nx;
      int k = q >> 9;
      int d4 = (q & 511) << 2;
      ushort4 o = {0, 0, 0, 0};
      if (k < count)
        o = cvt4(*(const float4*)(w1 + (long long)idx[k] * D + d4));
      *(ushort4*)(w1c + (long long)k * D + d4) = o;
    } else {
      int q = i - nx - nw1;
      int n = q >> 10;
      int k4 = (q & 1023) << 2;
      ushort4 o = {0, 0, 0, 0};
      const float* src = w2 + (long long)n * H;
#pragma unroll
      for (int u = 0; u < 4; ++u) {
        int k = k4 + u;
        unsigned short v = 0;
        if (k < count) v = f32_to_bf16_rn(src[idx[k]]);
        ((unsigned short*)&o)[u] = v;
      }
      *(ushort4*)(w2c + (long long)n * 4096 + k4) = o;
    }
  }
}

// ====== 128x128 tile, BK=64, 1024 blocks + circular-K stagger (CLEAN) =======
// The discovery (R15/R19 dispatch accounting): this engine at 4 blocks/CU
// (queue == residency, the convoy regime) runs 101us WITHOUT stagger (R12)
// and ~70us WITH the 4-group circular-K stagger — co-resident blocks (bid,
// +256, +512, +768) start the K-loop at {0, NT/4, NT/2, 3NT/4} (wrap-around;
// deterministic fp32-accum reorder), so one block's MFMA covers another's
// stage/barrier RTT. Both GEMMs here are shape-identical (8192x2048x2048).
// Swizzle (0-conflict, proven): phys granule = logical ^ (row&7); inverse on
// gl_lds SOURCE column; LDS linear; read gp = gA ^ 4kk.
template <int EPI>
__global__ __launch_bounds__(256, 4) void gemm_pool_kernel(
    const bf16_t* __restrict__ A, const bf16_t* __restrict__ B,
    void* __restrict__ Cout, long long ldA, long long ldB, long long ldC,
    int Kfix, int ncolFix, const int* __restrict__ meta) {
  const int kpad = meta[1];
  const int K = (EPI == 0) ? kpad : Kfix;               // GEMM2: K dynamic
  const int ncol = (EPI == 1) ? (kpad >> 7) : ncolFix;  // GEMM1: cols dynamic
  const int ntiles = ncol << 6;                         // nrow = 64
  const int NT = K >> 6;
  const int phase = ((blockIdx.x >> 8) & 3) * (NT >> 2);

  __shared__ bf16_t As[128 * 64];  // 16 KB
  __shared__ bf16_t Bs[128 * 64];  // 16 KB

  const int tid = threadIdx.x;
  const int l = tid & 63;
  const int w = tid >> 6;
  const int wm = w >> 1;  // 0..1 : 64-row half
  const int wn = w & 1;   // 0..1 : 64-col half

  const int srow = tid >> 3;                          // 0..31
  const int sg = ((tid & 7) ^ ((tid >> 3) & 7)) * 8;  // src col elems

  const int fr = l & 15;
  const int gA = (l >> 4) ^ (l & 7);

  for (int tau = blockIdx.x; tau < ntiles; tau += gridDim.x) {
    const int row = tau & 63;
    const int col = tau >> 6;
    const long long brow = (long long)row * 128;
    const long long bcol = (long long)col * 128;

    const bf16_t* Ag = A + (brow + srow) * ldA + sg;
    const bf16_t* Bg = B + (bcol + srow) * ldB + sg;

    f32x4 acc[4][4];
#pragma unroll
    for (int m = 0; m < 4; ++m)
#pragma unroll
      for (int n = 0; n < 4; ++n) acc[m][n] = (f32x4){0.f, 0.f, 0.f, 0.f};

    for (int it = 0; it < NT; ++it) {
      int t = it + phase;
      if (t >= NT) t -= NT;
      const int k0 = t << 6;
      GLDS16(Ag + k0, &As[tid * 8]);
      GLDS16(Ag + 32 * ldA + k0, &As[2048 + tid * 8]);
      GLDS16(Ag + 64 * ldA + k0, &As[4096 + tid * 8]);
      GLDS16(Ag + 96 * ldA + k0, &As[6144 + tid * 8]);
      GLDS16(Bg + k0, &Bs[tid * 8]);
      GLDS16(Bg + 32 * ldB + k0, &Bs[2048 + tid * 8]);
      GLDS16(Bg + 64 * ldB + k0, &Bs[4096 + tid * 8]);
      GLDS16(Bg + 96 * ldB + k0, &Bs[6144 + tid * 8]);
      __syncthreads();
#pragma unroll
      for (int kk = 0; kk < 2; ++kk) {
        const int gp = (gA ^ (kk * 4)) * 8;
        bf16x8 af[4], bfr[4];
#pragma unroll
        for (int m = 0; m < 4; ++m)
          af[m] = *(const bf16x8*)(&As[(wm * 64 + m * 16 + fr) * 64 + gp]);
#pragma unroll
        for (int n = 0; n < 4; ++n)
          bfr[n] = *(const bf16x8*)(&Bs[(wn * 64 + n * 16 + fr) * 64 + gp]);
#pragma unroll
        for (int m = 0; m < 4; ++m)
#pragma unroll
          for (int n = 0; n < 4; ++n)
            acc[m][n] = __builtin_amdgcn_mfma_f32_16x16x32_bf16(
                af[m], bfr[n], acc[m][n], 0, 0, 0);
      }
      __syncthreads();
    }

    const int orow = wm * 64 + (l >> 4) * 4;
    const int ocol = wn * 64 + fr;
#pragma unroll
    for (int m = 0; m < 4; ++m)
#pragma unroll
      for (int n = 0; n < 4; ++n)
#pragma unroll
        for (int r = 0; r < 4; ++r) {
          long long rr = brow + orow + m * 16 + r;
          long long cc = bcol + ocol + n * 16;
          float v = acc[m][n][r];
          if (EPI == 1) {
            ((unsigned short*)Cout)[rr * ldC + cc] =
                f32_to_bf16_rn(gelu_exact(v));
          } else {
            ((float*)Cout)[rr * ldC + cc] = v;
          }
        }
  }
}

extern "C" void kernel_launch(void* const* d_in, const int* in_sizes, int n_in,
                              void* d_out, int out_size, void* d_ws,
                              size_t ws_size, hipStream_t stream) {
  const float* x = (const float*)d_in[0];
  const float* w1 = (const float*)d_in[1];
  const float* w2 = (const float*)d_in[2];
  const float* mask1 = (const float*)d_in[3];
  const float* mask2 = (const float*)d_in[4];
  float* out = (float*)d_out;

  const int D = 2048, H = 8192, M = 8192;
  const int KP = 4096;

  char* ws = (char*)d_ws;
  unsigned short* xb = (unsigned short*)ws;
  unsigned short* w1c = xb + (size_t)M * D;
  unsigned short* w2c = w1c + (size_t)KP * D;
  unsigned short* hb = w2c + (size_t)D * KP;
  int* idx = (int*)(hb + (size_t)M * KP);
  int* meta = idx + KP;

  build_idx_kernel<<<1, 1024, 0, stream>>>(mask1, mask2, idx, meta, H, D);

  // fused prep: cast x, compact+cast w1, compact+cast w2
  prep_kernel<<<2048, 256, 0, stream>>>(x, w1, w2, idx, meta, xb, w1c, w2c, D,
                                        H);

  // GEMM1: h[:, 0:kpad] = gelu(x @ w1c^T). K=2048 fixed; ncol = kpad/128 (dev)
  gemm_pool_kernel<1><<<1024, 256, 0, stream>>>(
      (const bf16_t*)xb, (const bf16_t*)w1c, hb, (long long)D, (long long)D,
      (long long)KP, D, 0, meta);

  // GEMM2: out = h @ w2c^T. K = kpad (dev); ncol = 2048/128 = 16 fixed
  gemm_pool_kernel<0><<<1024, 256, 0, stream>>>(
      (const bf16_t*)hb, (const bf16_t*)w2c, out, (long long)KP,
      (long long)KP, (long long)D, 0, 16, meta);
}

// Round 21
// 226.552 us; speedup vs baseline: 1.0632x; 1.0632x over previous
//
#include <hip/hip_runtime.h>
#include <hip/hip_bf16.h>

typedef __bf16 bf16_t;
typedef __bf16 bf16x8 __attribute__((ext_vector_type(8)));
typedef float f32x4 __attribute__((ext_vector_type(4)));

__device__ __forceinline__ unsigned short f32_to_bf16_rn(float f) {
  unsigned u = __float_as_uint(f);
  u += 0x7fffu + ((u >> 16) & 1u);
  return (unsigned short)(u >> 16);
}

__device__ __forceinline__ ushort4 cvt4(float4 v) {
  ushort4 o;
  o.x = f32_to_bf16_rn(v.x);
  o.y = f32_to_bf16_rn(v.y);
  o.z = f32_to_bf16_rn(v.z);
  o.w = f32_to_bf16_rn(v.w);
  return o;
}

__device__ __forceinline__ float gelu_exact(float x) {
  return 0.5f * x * (1.0f + erff(x * 0.7071067811865475f));
}

#define GLDS16(g, l)                                                          \
  __builtin_amdgcn_global_load_lds(                                           \
      (const __attribute__((address_space(1))) void*)(g),                     \
      (__attribute__((address_space(3))) void*)(l), 16, 0, 0)

// ---------------- build compacted index list (deterministic scan) ----------
__global__ void build_idx_kernel(const float* __restrict__ mask1,
                                 const float* __restrict__ mask2,
                                 int* __restrict__ idx, int* __restrict__ meta,
                                 int H, int D) {
  __shared__ int sums[1024];
  const int t = threadIdx.x;
  int flags[8];
  int tot = 0;
#pragma unroll
  for (int u = 0; u < 8; ++u) {
    int j = t * 8 + u;
    int f = (mask1[(long long)j * D] != 0.0f) && (mask2[j] != 0.0f);
    flags[u] = f;
    tot += f;
  }
  sums[t] = tot;
  __syncthreads();
  for (int off = 1; off < 1024; off <<= 1) {
    int v = (t >= off) ? sums[t - off] : 0;
    __syncthreads();
    sums[t] += v;
    __syncthreads();
  }
  int pos = sums[t] - tot;
#pragma unroll
  for (int u = 0; u < 8; ++u) {
    if (flags[u]) idx[pos++] = t * 8 + u;
  }
  if (t == 1023) {
    int count = sums[1023];
    meta[0] = count;
    meta[1] = (count + 127) & ~127;  // kpad: multiple of 128
  }
}

// -------- fused prep: cast x -> bf16  AND  compact+cast w1 rows ------------
// w1 gather LAST so w1c (8MB, L2-fits) is hot when GEMM1 starts.
__global__ void prep_kernel(const float* __restrict__ x,
                            const float* __restrict__ w1,
                            const int* __restrict__ idx,
                            const int* __restrict__ meta,
                            unsigned short* __restrict__ xb,
                            unsigned short* __restrict__ w1c, int D) {
  const int nx = 4194304;  // M*D/4 quads
  const int count = meta[0];
  const int kpad = meta[1];
  const int nw1 = kpad << 9;  // kpad * D/4 quads
  for (int i = blockIdx.x * 256 + threadIdx.x; i < nx + nw1; i += 2048 * 256) {
    if (i < nx) {
      ((ushort4*)xb)[i] = cvt4(((const float4*)x)[i]);
    } else {
      int q = i - nx;
      int k = q >> 9;
      int d4 = (q & 511) << 2;
      ushort4 o = {0, 0, 0, 0};
      if (k < count)
        o = cvt4(*(const float4*)(w1 + (long long)idx[k] * D + d4));
      *(ushort4*)(w1c + (long long)k * D + d4) = o;
    }
  }
}

// ====== 128x128 tile, BK=64, 1024 blocks + circular-K stagger ===============
// Engine: R12/R20 proven (0 bank conflicts, ~97us). DOW2==1 (GEMM1): every
// block runs a TINY grid-strided w2-gather prologue (~2KB/block, ~80MB total,
// done in the kernel's first few us) so w2c (16MB, L2-fits) is L2-HOT when
// GEMM2 launches. Four-round A/B (R15/R19 vs R16/R20): w2c-hot GEMM2 ~70us
// vs w2c-cold ~97us; the old 512-block piggyback achieved this warmth but
// cost GEMM1 +37us of all-kernel interference — the prologue form spreads
// the same work across all 1024 blocks with no residency shift.
// Stagger: co-resident blocks (bid, +256, +512, +768) start the K-loop at
// {0, NT/4, NT/2, 3NT/4} (wrap-around; deterministic fp32-accum reorder).
// Swizzle: phys granule = logical ^ (row&7); inverse on gl_lds SOURCE col;
// LDS linear; read gp = gA ^ 4kk.
template <int EPI, int DOW2>
__global__ __launch_bounds__(256, 4) void gemm_pool_kernel(
    const bf16_t* __restrict__ A, const bf16_t* __restrict__ B,
    void* __restrict__ Cout, long long ldA, long long ldB, long long ldC,
    int Kfix, int ncolFix, const int* __restrict__ meta,
    const float* __restrict__ w2src, const int* __restrict__ idx,
    unsigned short* __restrict__ w2c, int H) {
  const int kpad = meta[1];

  if (DOW2) {
    // ---- w2-gather prologue: all blocks, ~4 iterations each ----
    const int count = meta[0];
    const int kq = kpad >> 2;       // quads per n-row
    const int nq2 = 2048 * kq;      // total quads (cols 0..kpad only)
    for (int q = blockIdx.x * 256 + threadIdx.x; q < nq2; q += 1024 * 256) {
      int n = q / kq;
      int k4 = (q - n * kq) << 2;
      ushort4 o = {0, 0, 0, 0};
      const float* src = w2src + (long long)n * H;
#pragma unroll
      for (int u = 0; u < 4; ++u) {
        int k = k4 + u;
        unsigned short v = 0;
        if (k < count) v = f32_to_bf16_rn(src[idx[k]]);
        ((unsigned short*)&o)[u] = v;
      }
      *(ushort4*)(w2c + (long long)n * 4096 + k4) = o;
    }
    // no barrier needed: w2c is only read by the NEXT kernel (GEMM2)
  }

  const int K = (EPI == 0) ? kpad : Kfix;               // GEMM2: K dynamic
  const int ncol = (EPI == 1) ? (kpad >> 7) : ncolFix;  // GEMM1: cols dynamic
  const int ntiles = ncol << 6;                         // nrow = 64
  const int NT = K >> 6;
  const int phase = ((blockIdx.x >> 8) & 3) * (NT >> 2);

  __shared__ bf16_t As[128 * 64];  // 16 KB
  __shared__ bf16_t Bs[128 * 64];  // 16 KB

  const int tid = threadIdx.x;
  const int l = tid & 63;
  const int w = tid >> 6;
  const int wm = w >> 1;  // 0..1 : 64-row half
  const int wn = w & 1;   // 0..1 : 64-col half

  const int srow = tid >> 3;                          // 0..31
  const int sg = ((tid & 7) ^ ((tid >> 3) & 7)) * 8;  // src col elems

  const int fr = l & 15;
  const int gA = (l >> 4) ^ (l & 7);

  for (int tau = blockIdx.x; tau < ntiles; tau += gridDim.x) {
    const int row = tau & 63;
    const int col = tau >> 6;
    const long long brow = (long long)row * 128;
    const long long bcol = (long long)col * 128;

    const bf16_t* Ag = A + (brow + srow) * ldA + sg;
    const bf16_t* Bg = B + (bcol + srow) * ldB + sg;

    f32x4 acc[4][4];
#pragma unroll
    for (int m = 0; m < 4; ++m)
#pragma unroll
      for (int n = 0; n < 4; ++n) acc[m][n] = (f32x4){0.f, 0.f, 0.f, 0.f};

    for (int it = 0; it < NT; ++it) {
      int t = it + phase;
      if (t >= NT) t -= NT;
      const int k0 = t << 6;
      GLDS16(Ag + k0, &As[tid * 8]);
      GLDS16(Ag + 32 * ldA + k0, &As[2048 + tid * 8]);
      GLDS16(Ag + 64 * ldA + k0, &As[4096 + tid * 8]);
      GLDS16(Ag + 96 * ldA + k0, &As[6144 + tid * 8]);
      GLDS16(Bg + k0, &Bs[tid * 8]);
      GLDS16(Bg + 32 * ldB + k0, &Bs[2048 + tid * 8]);
      GLDS16(Bg + 64 * ldB + k0, &Bs[4096 + tid * 8]);
      GLDS16(Bg + 96 * ldB + k0, &Bs[6144 + tid * 8]);
      __syncthreads();
#pragma unroll
      for (int kk = 0; kk < 2; ++kk) {
        const int gp = (gA ^ (kk * 4)) * 8;
        bf16x8 af[4], bfr[4];
#pragma unroll
        for (int m = 0; m < 4; ++m)
          af[m] = *(const bf16x8*)(&As[(wm * 64 + m * 16 + fr) * 64 + gp]);
#pragma unroll
        for (int n = 0; n < 4; ++n)
          bfr[n] = *(const bf16x8*)(&Bs[(wn * 64 + n * 16 + fr) * 64 + gp]);
#pragma unroll
        for (int m = 0; m < 4; ++m)
#pragma unroll
          for (int n = 0; n < 4; ++n)
            acc[m][n] = __builtin_amdgcn_mfma_f32_16x16x32_bf16(
                af[m], bfr[n], acc[m][n], 0, 0, 0);
      }
      __syncthreads();
    }

    const int orow = wm * 64 + (l >> 4) * 4;
    const int ocol = wn * 64 + fr;
#pragma unroll
    for (int m = 0; m < 4; ++m)
#pragma unroll
      for (int n = 0; n < 4; ++n)
#pragma unroll
        for (int r = 0; r < 4; ++r) {
          long long rr = brow + orow + m * 16 + r;
          long long cc = bcol + ocol + n * 16;
          float v = acc[m][n][r];
          if (EPI == 1) {
            ((unsigned short*)Cout)[rr * ldC + cc] =
                f32_to_bf16_rn(gelu_exact(v));
          } else {
            ((float*)Cout)[rr * ldC + cc] = v;
          }
        }
  }
}

extern "C" void kernel_launch(void* const* d_in, const int* in_sizes, int n_in,
                              void* d_out, int out_size, void* d_ws,
                              size_t ws_size, hipStream_t stream) {
  const float* x = (const float*)d_in[0];
  const float* w1 = (const float*)d_in[1];
  const float* w2 = (const float*)d_in[2];
  const float* mask1 = (const float*)d_in[3];
  const float* mask2 = (const float*)d_in[4];
  float* out = (float*)d_out;

  const int D = 2048, H = 8192, M = 8192;
  const int KP = 4096;

  char* ws = (char*)d_ws;
  unsigned short* xb = (unsigned short*)ws;
  unsigned short* w1c = xb + (size_t)M * D;
  unsigned short* w2c = w1c + (size_t)KP * D;
  unsigned short* hb = w2c + (size_t)D * KP;
  int* idx = (int*)(hb + (size_t)M * KP);
  int* meta = idx + KP;

  build_idx_kernel<<<1, 1024, 0, stream>>>(mask1, mask2, idx, meta, H, D);

  // fused prep: cast x, compact+cast w1 (w1c last -> hot for GEMM1)
  prep_kernel<<<2048, 256, 0, stream>>>(x, w1, idx, meta, xb, w1c, D);

  // GEMM1 (+ w2-gather prologue spread across its 1024 blocks):
  // h[:, 0:kpad] = gelu(x @ w1c^T). K=2048 fixed; ncol = kpad/128 (device)
  gemm_pool_kernel<1, 1><<<1024, 256, 0, stream>>>(
      (const bf16_t*)xb, (const bf16_t*)w1c, hb, (long long)D, (long long)D,
      (long long)KP, D, 0, meta, w2, idx, w2c, H);

  // GEMM2: out = h @ w2c^T. K = kpad (device); ncol = 2048/128 = 16 fixed
  gemm_pool_kernel<0, 0><<<1024, 256, 0, stream>>>(
      (const bf16_t*)hb, (const bf16_t*)w2c, out, (long long)KP,
      (long long)KP, (long long)D, 0, 16, meta, nullptr, nullptr, nullptr, H);
}

// Round 22
// 223.897 us; speedup vs baseline: 1.0758x; 1.0119x over previous
//
#include <hip/hip_runtime.h>
#include <hip/hip_bf16.h>

typedef __bf16 bf16_t;
typedef __bf16 bf16x8 __attribute__((ext_vector_type(8)));
typedef float f32x4 __attribute__((ext_vector_type(4)));

__device__ __forceinline__ unsigned short f32_to_bf16_rn(float f) {
  unsigned u = __float_as_uint(f);
  u += 0x7fffu + ((u >> 16) & 1u);
  return (unsigned short)(u >> 16);
}

__device__ __forceinline__ ushort4 cvt4(float4 v) {
  ushort4 o;
  o.x = f32_to_bf16_rn(v.x);
  o.y = f32_to_bf16_rn(v.y);
  o.z = f32_to_bf16_rn(v.z);
  o.w = f32_to_bf16_rn(v.w);
  return o;
}

__device__ __forceinline__ float gelu_exact(float x) {
  return 0.5f * x * (1.0f + erff(x * 0.7071067811865475f));
}

#define GLDS16(g, l)                                                          \
  __builtin_amdgcn_global_load_lds(                                           \
      (const __attribute__((address_space(1))) void*)(g),                     \
      (__attribute__((address_space(3))) void*)(l), 16, 0, 0)

// ---------------- build compacted index list (deterministic scan) ----------
__global__ void build_idx_kernel(const float* __restrict__ mask1,
                                 const float* __restrict__ mask2,
                                 int* __restrict__ idx, int* __restrict__ meta,
                                 int H, int D) {
  __shared__ int sums[1024];
  const int t = threadIdx.x;
  int flags[8];
  int tot = 0;
#pragma unroll
  for (int u = 0; u < 8; ++u) {
    int j = t * 8 + u;
    int f = (mask1[(long long)j * D] != 0.0f) && (mask2[j] != 0.0f);
    flags[u] = f;
    tot += f;
  }
  sums[t] = tot;
  __syncthreads();
  for (int off = 1; off < 1024; off <<= 1) {
    int v = (t >= off) ? sums[t - off] : 0;
    __syncthreads();
    sums[t] += v;
    __syncthreads();
  }
  int pos = sums[t] - tot;
#pragma unroll
  for (int u = 0; u < 8; ++u) {
    if (flags[u]) idx[pos++] = t * 8 + u;
  }
  if (t == 1023) {
    int count = sums[1023];
    meta[0] = count;
    meta[1] = (count + 127) & ~127;  // kpad: multiple of 128
  }
}

// -------- fused prep: compact+cast w1 rows FIRST, cast x -> bf16 LAST ------
// Order matters for L2 warmth: xb (32MB = aggregate L2) is GEMM1's A operand;
// writing it LAST leaves it L2-dirty-hot when GEMM1 launches (the R15/R19/R21
// warmth effect: fresh-dirty operands gave GEMM2 ~67us vs ~97us cold).
__global__ void prep_kernel(const float* __restrict__ x,
                            const float* __restrict__ w1,
                            const int* __restrict__ idx,
                            const int* __restrict__ meta,
                            unsigned short* __restrict__ xb,
                            unsigned short* __restrict__ w1c, int D) {
  const int nx = 4194304;  // M*D/4 quads
  const int count = meta[0];
  const int kpad = meta[1];
  const int nw1 = kpad << 9;  // kpad * D/4 quads
  for (int i = blockIdx.x * 256 + threadIdx.x; i < nw1 + nx; i += 2048 * 256) {
    if (i < nw1) {
      int k = i >> 9;
      int d4 = (i & 511) << 2;
      ushort4 o = {0, 0, 0, 0};
      if (k < count)
        o = cvt4(*(const float4*)(w1 + (long long)idx[k] * D + d4));
      *(ushort4*)(w1c + (long long)k * D + d4) = o;
    } else {
      int q = i - nw1;
      ((ushort4*)xb)[q] = cvt4(((const float4*)x)[q]);
    }
  }
}

// ---- per-block share of the w2 gather (same q->block owner as R21) --------
__device__ __forceinline__ void w2_gather_share(
    const float* __restrict__ w2src, const int* __restrict__ idx,
    unsigned short* __restrict__ w2c, int count, int kpad, int H, int bid,
    int tid) {
  const int kq = kpad >> 2;   // quads per n-row
  const int nq2 = 2048 * kq;  // total quads (cols 0..kpad only)
  for (int q = bid * 256 + tid; q < nq2; q += 1024 * 256) {
    int n = q / kq;
    int k4 = (q - n * kq) << 2;
    ushort4 o = {0, 0, 0, 0};
    const float* src = w2src + (long long)n * H;
#pragma unroll
    for (int u = 0; u < 4; ++u) {
      int k = k4 + u;
      unsigned short v = 0;
      if (k < count) v = f32_to_bf16_rn(src[idx[k]]);
      ((unsigned short*)&o)[u] = v;
    }
    *(ushort4*)(w2c + (long long)n * 4096 + k4) = o;
  }
}

// ====== 128x128 tile, BK=64, 1024 blocks + circular-K stagger ===============
// Engine: R12/R20 proven (0 bank conflicts). DOW2==1 (GEMM1): w2-gather split
// — EVEN blocks gather before their K-loop, ODD blocks after their C-write —
// so half the ~20us gather hides under other blocks' compute instead of
// running as a serial front (R21 paid the full cost up front: +26us).
// w2c has no reader until GEMM2 (next kernel), so either order is race-free
// and deterministic (q->owner partition unchanged).
// Stagger: co-resident blocks (bid, +256, +512, +768) start the K-loop at
// {0, NT/4, NT/2, 3NT/4} (wrap-around; deterministic fp32-accum reorder).
// Swizzle: phys granule = logical ^ (row&7); inverse on gl_lds SOURCE col;
// LDS linear; read gp = gA ^ 4kk.
template <int EPI, int DOW2>
__global__ __launch_bounds__(256, 4) void gemm_pool_kernel(
    const bf16_t* __restrict__ A, const bf16_t* __restrict__ B,
    void* __restrict__ Cout, long long ldA, long long ldB, long long ldC,
    int Kfix, int ncolFix, const int* __restrict__ meta,
    const float* __restrict__ w2src, const int* __restrict__ idx,
    unsigned short* __restrict__ w2c, int H) {
  const int kpad = meta[1];

  if (DOW2 && !(blockIdx.x & 1))
    w2_gather_share(w2src, idx, w2c, meta[0], kpad, H, blockIdx.x,
                    threadIdx.x);

  const int K = (EPI == 0) ? kpad : Kfix;               // GEMM2: K dynamic
  const int ncol = (EPI == 1) ? (kpad >> 7) : ncolFix;  // GEMM1: cols dynamic
  const int ntiles = ncol << 6;                         // nrow = 64
  const int NT = K >> 6;
  const int phase = ((blockIdx.x >> 8) & 3) * (NT >> 2);

  __shared__ bf16_t As[128 * 64];  // 16 KB
  __shared__ bf16_t Bs[128 * 64];  // 16 KB

  const int tid = threadIdx.x;
  const int l = tid & 63;
  const int w = tid >> 6;
  const int wm = w >> 1;  // 0..1 : 64-row half
  const int wn = w & 1;   // 0..1 : 64-col half

  const int srow = tid >> 3;                          // 0..31
  const int sg = ((tid & 7) ^ ((tid >> 3) & 7)) * 8;  // src col elems

  const int fr = l & 15;
  const int gA = (l >> 4) ^ (l & 7);

  for (int tau = blockIdx.x; tau < ntiles; tau += gridDim.x) {
    const int row = tau & 63;
    const int col = tau >> 6;
    const long long brow = (long long)row * 128;
    const long long bcol = (long long)col * 128;

    const bf16_t* Ag = A + (brow + srow) * ldA + sg;
    const bf16_t* Bg = B + (bcol + srow) * ldB + sg;

    f32x4 acc[4][4];
#pragma unroll
    for (int m = 0; m < 4; ++m)
#pragma unroll
      for (int n = 0; n < 4; ++n) acc[m][n] = (f32x4){0.f, 0.f, 0.f, 0.f};

    for (int it = 0; it < NT; ++it) {
      int t = it + phase;
      if (t >= NT) t -= NT;
      const int k0 = t << 6;
      GLDS16(Ag + k0, &As[tid * 8]);
      GLDS16(Ag + 32 * ldA + k0, &As[2048 + tid * 8]);
      GLDS16(Ag + 64 * ldA + k0, &As[4096 + tid * 8]);
      GLDS16(Ag + 96 * ldA + k0, &As[6144 + tid * 8]);
      GLDS16(Bg + k0, &Bs[tid * 8]);
      GLDS16(Bg + 32 * ldB + k0, &Bs[2048 + tid * 8]);
      GLDS16(Bg + 64 * ldB + k0, &Bs[4096 + tid * 8]);
      GLDS16(Bg + 96 * ldB + k0, &Bs[6144 + tid * 8]);
      __syncthreads();
#pragma unroll
      for (int kk = 0; kk < 2; ++kk) {
        const int gp = (gA ^ (kk * 4)) * 8;
        bf16x8 af[4], bfr[4];
#pragma unroll
        for (int m = 0; m < 4; ++m)
          af[m] = *(const bf16x8*)(&As[(wm * 64 + m * 16 + fr) * 64 + gp]);
#pragma unroll
        for (int n = 0; n < 4; ++n)
          bfr[n] = *(const bf16x8*)(&Bs[(wn * 64 + n * 16 + fr) * 64 + gp]);
#pragma unroll
        for (int m = 0; m < 4; ++m)
#pragma unroll
          for (int n = 0; n < 4; ++n)
            acc[m][n] = __builtin_amdgcn_mfma_f32_16x16x32_bf16(
                af[m], bfr[n], acc[m][n], 0, 0, 0);
      }
      __syncthreads();
    }

    const int orow = wm * 64 + (l >> 4) * 4;
    const int ocol = wn * 64 + fr;
#pragma unroll
    for (int m = 0; m < 4; ++m)
#pragma unroll
      for (int n = 0; n < 4; ++n)
#pragma unroll
        for (int r = 0; r < 4; ++r) {
          long long rr = brow + orow + m * 16 + r;
          long long cc = bcol + ocol + n * 16;
          float v = acc[m][n][r];
          if (EPI == 1) {
            ((unsigned short*)Cout)[rr * ldC + cc] =
                f32_to_bf16_rn(gelu_exact(v));
          } else {
            ((float*)Cout)[rr * ldC + cc] = v;
          }
        }
  }

  if (DOW2 && (blockIdx.x & 1))
    w2_gather_share(w2src, idx, w2c, meta[0], kpad, H, blockIdx.x,
                    threadIdx.x);
}

extern "C" void kernel_launch(void* const* d_in, const int* in_sizes, int n_in,
                              void* d_out, int out_size, void* d_ws,
                              size_t ws_size, hipStream_t stream) {
  const float* x = (const float*)d_in[0];
  const float* w1 = (const float*)d_in[1];
  const float* w2 = (const float*)d_in[2];
  const float* mask1 = (const float*)d_in[3];
  const float* mask2 = (const float*)d_in[4];
  float* out = (float*)d_out;

  const int D = 2048, H = 8192, M = 8192;
  const int KP = 4096;

  char* ws = (char*)d_ws;
  unsigned short* xb = (unsigned short*)ws;
  unsigned short* w1c = xb + (size_t)M * D;
  unsigned short* w2c = w1c + (size_t)KP * D;
  unsigned short* hb = w2c + (size_t)D * KP;
  int* idx = (int*)(hb + (size_t)M * KP);
  int* meta = idx + KP;

  build_idx_kernel<<<1, 1024, 0, stream>>>(mask1, mask2, idx, meta, H, D);

  // fused prep: w1 gather FIRST, x cast LAST (xb L2-hot for GEMM1)
  prep_kernel<<<2048, 256, 0, stream>>>(x, w1, idx, meta, xb, w1c, D);

  // GEMM1 (+ split w2-gather: even blocks pre-loop, odd blocks post-loop):
  // h[:, 0:kpad] = gelu(x @ w1c^T). K=2048 fixed; ncol = kpad/128 (device)
  gemm_pool_kernel<1, 1><<<1024, 256, 0, stream>>>(
      (const bf16_t*)xb, (const bf16_t*)w1c, hb, (long long)D, (long long)D,
      (long long)KP, D, 0, meta, w2, idx, w2c, H);

  // GEMM2: out = h @ w2c^T. K = kpad (device); ncol = 2048/128 = 16 fixed
  gemm_pool_kernel<0, 0><<<1024, 256, 0, stream>>>(
      (const bf16_t*)hb, (const bf16_t*)w2c, out, (long long)KP,
      (long long)KP, (long long)D, 0, 16, meta, nullptr, nullptr, nullptr, H);
}